// Round 1
// baseline (1188.674 us; speedup 1.0000x reference)
//
#include <hip/hip_runtime.h>
#include <hip/hip_bf16.h>

// Problem constants (fixed by setup_inputs)
#define TT 16      // in_length
#define EE 32      // embedding size
#define HH 64      // encoder size
#define NGRP 32    // vehicles per group
#define CC 3       // classes

__device__ __forceinline__ float leakyf(float x) { return fmaxf(x, 0.1f * x); }
__device__ __forceinline__ float sigmoidf_fast(float x) {
    return __builtin_amdgcn_rcpf(1.0f + __expf(-x));
}
__device__ __forceinline__ float tanhf_fast(float x) {
    // tanh(x) = 1 - 2/(exp(2x)+1);  exp->inf => 1, exp->0 => -1 : saturates correctly
    return 1.0f - 2.0f * __builtin_amdgcn_rcpf(__expf(2.0f * x) + 1.0f);
}

// ---------------------------------------------------------------------------
// Kernel A: embedding + forward GRU + backward GRU + seq_enc
// Block: 256 threads = 4 waves. Wave q handles output dims j in [q*16, q*16+16)
// for 64 vehicles (lane = vehicle). h kept in LDS transposed [k][veh].
// Writes seq_enc into full_enc[n][0..31].
// ---------------------------------------------------------------------------
__global__ __launch_bounds__(256) void gru_kernel(
    const float* __restrict__ scene,
    const float* __restrict__ W_emb, const float* __restrict__ b_emb,
    const float* __restrict__ Wih_f, const float* __restrict__ Whh_f,
    const float* __restrict__ bih_f, const float* __restrict__ bhh_f,
    const float* __restrict__ Wih_b, const float* __restrict__ Whh_b,
    const float* __restrict__ bih_b, const float* __restrict__ bhh_b,
    const float* __restrict__ Wm, const float* __restrict__ bm,
    float* __restrict__ full_enc)
{
    __shared__ float sh_h[2][HH][64];     // double-buffered hidden, [k][veh]
    __shared__ float sh_hf[HH][64];       // forward final hidden
    __shared__ float sh_scene[2 * TT][64];// scene transposed [col][veh]

    const int tid  = threadIdx.x;
    const int lane = tid & 63;                                   // vehicle in block
    const int q    = __builtin_amdgcn_readfirstlane(tid >> 6);   // wave-uniform quarter
    const int vbase = blockIdx.x * 64;

    // Stage scene rows (coalesced read, transposed store)
    for (int idx = tid; idx < 64 * 2 * TT; idx += 256) {
        int v = idx >> 5, c = idx & 31;
        sh_scene[c][v] = scene[(vbase + v) * (2 * TT) + c];
    }
    __syncthreads();

    #pragma unroll 1
    for (int dir = 0; dir < 2; ++dir) {
        const float* Wih = dir ? Wih_b : Wih_f;
        const float* Whh = dir ? Whh_b : Whh_f;
        const float* bih = dir ? bih_b : bih_f;
        const float* bhh = dir ? bhh_b : bhh_f;

        // zero-init h (buffer 0)
        for (int k = q; k < HH; k += 4) sh_h[0][k][lane] = 0.0f;
        __syncthreads();

        int cur = 0;
        #pragma unroll 1
        for (int s = 0; s < TT; ++s) {
            const int t = dir ? (TT - 1 - s) : s;

            // load full hidden into registers (conflict-free b32 reads)
            float hreg[HH];
            #pragma unroll
            for (int k = 0; k < HH; ++k) hreg[k] = sh_h[cur][k][lane];

            // embedding for this (t, vehicle): leaky(x*W0 + y*W1 + b)
            const float xs = sh_scene[t][lane];
            const float ys = sh_scene[TT + t][lane];
            float emb[EE];
            #pragma unroll
            for (int e = 0; e < EE; ++e)
                emb[e] = leakyf(fmaf(xs, W_emb[e], fmaf(ys, W_emb[EE + e], b_emb[e])));

            #pragma unroll 1
            for (int jj = 0; jj < 16; ++jj) {
                const int j = q * 16 + jj;   // wave-uniform
                float xr = bih[j], xz = bih[j + HH], xn = bih[j + 2 * HH];
                const float* wr = Wih + j * EE;
                const float* wz = Wih + (j + HH) * EE;
                const float* wn = Wih + (j + 2 * HH) * EE;
                #pragma unroll
                for (int e = 0; e < EE; ++e) {
                    xr = fmaf(emb[e], wr[e], xr);
                    xz = fmaf(emb[e], wz[e], xz);
                    xn = fmaf(emb[e], wn[e], xn);
                }
                float hr = bhh[j], hz = bhh[j + HH], hn = bhh[j + 2 * HH];
                const float* vr = Whh + j * HH;
                const float* vz = Whh + (j + HH) * HH;
                const float* vn = Whh + (j + 2 * HH) * HH;
                #pragma unroll
                for (int k = 0; k < HH; ++k) {
                    hr = fmaf(hreg[k], vr[k], hr);
                    hz = fmaf(hreg[k], vz[k], hz);
                    hn = fmaf(hreg[k], vn[k], hn);
                }
                const float r  = sigmoidf_fast(xr + hr);
                const float z  = sigmoidf_fast(xz + hz);
                const float ng = tanhf_fast(fmaf(r, hn, xn));
                const float hold = sh_h[cur][j][lane];  // dynamic j: read from LDS
                sh_h[cur ^ 1][j][lane] = fmaf(z, hold - ng, ng); // (1-z)*ng + z*h
            }
            __syncthreads();
            cur ^= 1;
        }
        if (dir == 0) {
            // save forward final hidden (cur==0 after 16 flips)
            for (int k = q; k < HH; k += 4) sh_hf[k][lane] = sh_h[cur][k][lane];
            __syncthreads();
        }
    }
    // h_b is in sh_h[0]; h_f in sh_hf
    float hm[HH];
    #pragma unroll
    for (int k = 0; k < HH; ++k) hm[k] = 0.5f * (sh_hf[k][lane] + sh_h[0][k][lane]);

    // seq_enc = leaky(hm @ Wm + bm) ; Wm is (64, 32) row-major, out[m]=sum_k hm[k]*Wm[k*32+m]
    const int n = vbase + lane;
    #pragma unroll
    for (int mm = 0; mm < 8; ++mm) {
        const int m = q * 8 + mm;   // wave-uniform
        float acc = bm[m];
        #pragma unroll
        for (int k = 0; k < HH; ++k) acc = fmaf(hm[k], Wm[k * 32 + m], acc);
        full_enc[n * HH + m] = leakyf(acc);
    }
}

// ---------------------------------------------------------------------------
// Kernel B: spatial pairwise MLP with layer-1 factoring.
// One block per group. tid = j*8 + o ; thread sums i in {o, o+8, o+16, o+24}.
// pooled[j] written into full_enc[g*32+j][32..63].
// ---------------------------------------------------------------------------
__global__ __launch_bounds__(256) void spatial_kernel(
    const float* __restrict__ scene, const int* __restrict__ index_div,
    const float* __restrict__ Ws1, const float* __restrict__ bs1,
    const float* __restrict__ Ws2, const float* __restrict__ bs2,
    float* __restrict__ full_enc)
{
    __shared__ float sfeat[NGRP][33];   // +1 pad: conflict-free strided reads
    __shared__ float su[NGRP][65];      // u = feat @ Ws1, padded
    __shared__ float szero[32];

    const int g   = blockIdx.x;
    const int tid = threadIdx.x;

    // stage feat (gather via index_div), float4 coalesced
    {
        const int v  = tid >> 3;
        const int c0 = (tid & 7) * 4;
        const int n  = index_div[g * NGRP + v];
        const float4 f4 = *(const float4*)(scene + n * (2 * TT) + c0);
        sfeat[v][c0 + 0] = f4.x; sfeat[v][c0 + 1] = f4.y;
        sfeat[v][c0 + 2] = f4.z; sfeat[v][c0 + 3] = f4.w;
    }
    __syncthreads();

    // u[v][d] = sum_e feat[v][e] * Ws1[e][d]   (Ws1 is (32,64) row-major)
    {
        const int v  = tid >> 3;
        const int d0 = (tid & 7) * 8;
        float acc[8];
        #pragma unroll
        for (int i = 0; i < 8; ++i) acc[i] = 0.0f;
        #pragma unroll
        for (int e = 0; e < EE; ++e) {
            const float f = sfeat[v][e];
            #pragma unroll
            for (int i = 0; i < 8; ++i) acc[i] = fmaf(f, Ws1[e * 64 + d0 + i], acc[i]);
        }
        #pragma unroll
        for (int i = 0; i < 8; ++i) su[v][d0 + i] = acc[i];
    }
    // zero_enc[c] = leaky( leaky(bs1) @ Ws2 + bs2 )
    if (tid < 32) {
        float zs = bs2[tid];
        #pragma unroll
        for (int d = 0; d < HH; ++d) zs = fmaf(leakyf(bs1[d]), Ws2[d * 32 + tid], zs);
        szero[tid] = leakyf(zs);
    }
    __syncthreads();

    const int j = tid >> 3;
    const int o = tid & 7;

    float esum[32];
    #pragma unroll
    for (int c = 0; c < 32; ++c) esum[c] = 0.0f;

    // preload u_j
    float uj[HH];
    #pragma unroll
    for (int d = 0; d < HH; ++d) uj[d] = su[j][d];

    #pragma unroll 1
    for (int ii = 0; ii < 4; ++ii) {
        const int i = o + ii * 8;
        float pre[32];
        #pragma unroll
        for (int c = 0; c < 32; ++c) pre[c] = bs2[c];
        #pragma unroll 8
        for (int d = 0; d < HH; ++d) {
            const float a = leakyf(su[i][d] - uj[d] + bs1[d]);
            #pragma unroll
            for (int c = 0; c < 32; ++c) pre[c] = fmaf(a, Ws2[d * 32 + c], pre[c]);
        }
        #pragma unroll
        for (int c = 0; c < 32; ++c) esum[c] += leakyf(pre[c]);
    }

    // reduce over the 8 o-lanes (lanes j*8..j*8+7 are contiguous in the wave)
    #pragma unroll
    for (int off = 1; off < 8; off <<= 1) {
        #pragma unroll
        for (int c = 0; c < 32; ++c) esum[c] += __shfl_xor(esum[c], off, 64);
    }
    if (o == 0) {
        const int row = g * NGRP + j;
        #pragma unroll
        for (int c = 0; c < 32; ++c)
            full_enc[row * HH + 32 + c] = (esum[c] - szero[c]) * (1.0f / 31.0f);
    }
}

// ---------------------------------------------------------------------------
// Kernel C: head — x_logit = leaky(full_enc @ Wo1 + bo1) @ Wo2 + bo2
// ---------------------------------------------------------------------------
__global__ __launch_bounds__(256) void head_kernel(
    const float* __restrict__ full_enc,
    const float* __restrict__ Wo1, const float* __restrict__ bo1,
    const float* __restrict__ Wo2, const float* __restrict__ bo2,
    float* __restrict__ out)
{
    const int n = blockIdx.x * 256 + threadIdx.x;
    float t1[16];
    #pragma unroll
    for (int m = 0; m < 16; ++m) t1[m] = bo1[m];
    const float4* fe4 = (const float4*)(full_enc + n * HH);
    #pragma unroll
    for (int k4 = 0; k4 < 16; ++k4) {
        const float4 f = fe4[k4];
        const float fv[4] = {f.x, f.y, f.z, f.w};
        #pragma unroll
        for (int u = 0; u < 4; ++u) {
            const int k = k4 * 4 + u;
            #pragma unroll
            for (int m = 0; m < 16; ++m) t1[m] = fmaf(fv[u], Wo1[k * 16 + m], t1[m]);
        }
    }
    float l0 = bo2[0], l1 = bo2[1], l2 = bo2[2];
    #pragma unroll
    for (int m = 0; m < 16; ++m) {
        const float a = leakyf(t1[m]);
        l0 = fmaf(a, Wo2[m * 3 + 0], l0);
        l1 = fmaf(a, Wo2[m * 3 + 1], l1);
        l2 = fmaf(a, Wo2[m * 3 + 2], l2);
    }
    out[n * 3 + 0] = l0;
    out[n * 3 + 1] = l1;
    out[n * 3 + 2] = l2;
}

// ---------------------------------------------------------------------------
extern "C" void kernel_launch(void* const* d_in, const int* in_sizes, int n_in,
                              void* d_out, int out_size, void* d_ws, size_t ws_size,
                              hipStream_t stream) {
    const float* scene     = (const float*)d_in[0];
    // d_in[1..3]: condition / hero_pos_index / nbrs_pos_index — unused by reference
    const int*   index_div = (const int*)d_in[4];
    const float* W_emb = (const float*)d_in[5];
    const float* b_emb = (const float*)d_in[6];
    const float* Wih_f = (const float*)d_in[7];
    const float* Whh_f = (const float*)d_in[8];
    const float* bih_f = (const float*)d_in[9];
    const float* bhh_f = (const float*)d_in[10];
    const float* Wih_b = (const float*)d_in[11];
    const float* Whh_b = (const float*)d_in[12];
    const float* bih_b = (const float*)d_in[13];
    const float* bhh_b = (const float*)d_in[14];
    const float* Wm  = (const float*)d_in[15];
    const float* bm  = (const float*)d_in[16];
    const float* Ws1 = (const float*)d_in[17];
    const float* bs1 = (const float*)d_in[18];
    const float* Ws2 = (const float*)d_in[19];
    const float* bs2 = (const float*)d_in[20];
    const float* Wo1 = (const float*)d_in[21];
    const float* bo1 = (const float*)d_in[22];
    const float* Wo2 = (const float*)d_in[23];
    const float* bo2 = (const float*)d_in[24];

    const int N = in_sizes[0] / (2 * TT);   // 32768
    const int G = in_sizes[4] / NGRP;       // 1024

    float* out      = (float*)d_out;
    float* full_enc = out + (size_t)N * CC;

    gru_kernel<<<dim3(N / 64), dim3(256), 0, stream>>>(
        scene, W_emb, b_emb, Wih_f, Whh_f, bih_f, bhh_f,
        Wih_b, Whh_b, bih_b, bhh_b, Wm, bm, full_enc);

    spatial_kernel<<<dim3(G), dim3(256), 0, stream>>>(
        scene, index_div, Ws1, bs1, Ws2, bs2, full_enc);

    head_kernel<<<dim3(N / 256), dim3(256), 0, stream>>>(
        full_enc, Wo1, bo1, Wo2, bo2, out);
}

// Round 2
// 295.120 us; speedup vs baseline: 4.0278x; 4.0278x over previous
//
#include <hip/hip_runtime.h>
#include <hip/hip_bf16.h>

// Problem constants (fixed by setup_inputs)
#define TT 16      // in_length
#define EE 32      // embedding size
#define HH 64      // encoder size
#define NGRP 32    // vehicles per group
#define CC 3       // classes

typedef __attribute__((ext_vector_type(8))) short short8;
typedef __attribute__((ext_vector_type(4))) float floatx4;

#define MFMA16(a, b, c) __builtin_amdgcn_mfma_f32_16x16x32_bf16((a), (b), (c), 0, 0, 0)

__device__ __forceinline__ float leakyf(float x) { return fmaxf(x, 0.1f * x); }
__device__ __forceinline__ float sigmoidf_fast(float x) {
    return __builtin_amdgcn_rcpf(1.0f + __expf(-x));
}
__device__ __forceinline__ float tanhf_fast(float x) {
    return 1.0f - 2.0f * __builtin_amdgcn_rcpf(__expf(2.0f * x) + 1.0f);
}
__device__ __forceinline__ short f2bf(float x) {   // fp32 -> bf16 RNE
    unsigned u = __float_as_uint(x);
    return (short)((u + 0x7FFFu + ((u >> 16) & 1u)) >> 16);
}
__device__ __forceinline__ short8 ld8bf(const float* __restrict__ p) {
    const float4 a = *(const float4*)p;
    const float4 b = *(const float4*)(p + 4);
    short8 v;
    v[0] = f2bf(a.x); v[1] = f2bf(a.y); v[2] = f2bf(a.z); v[3] = f2bf(a.w);
    v[4] = f2bf(b.x); v[5] = f2bf(b.y); v[6] = f2bf(b.z); v[7] = f2bf(b.w);
    return v;
}

// ---------------------------------------------------------------------------
// Kernel A (MFMA): emb + fwd GRU + bwd GRU + seq_enc for 32 vehicles/block.
// Per step: gates = [H | X] @ W^T via mfma_f32_16x16x32_bf16.
//   A-frag: A[m=lane&15][k=(lane>>4)*8+i]  (m = vehicle, k = h-dim or emb-dim)
//   B-frag: B[k=(lane>>4)*8+i][n=lane&15]  (n = gate column j, per-lane weights in VGPRs)
//   C/D   : row(m)=(lane>>4)*4+reg, col(n)=lane&15   [measured m89]
// Wave w owns gate columns j in [16w,16w+16). h kept fp32 in C-layout regs;
// bf16 copy staged in frag-packed LDS (conflict-free ds_read_b128).
// n-gate keeps H-part and X-part in separate accumulators (ng = tanh(xn + r*hn)).
// ---------------------------------------------------------------------------
__global__ __launch_bounds__(256, 3) void gru_mfma_kernel(
    const float* __restrict__ scene,
    const float* __restrict__ W_emb, const float* __restrict__ b_emb,
    const float* __restrict__ Wih_f, const float* __restrict__ Whh_f,
    const float* __restrict__ bih_f, const float* __restrict__ bhh_f,
    const float* __restrict__ Wih_b, const float* __restrict__ Whh_b,
    const float* __restrict__ bih_b, const float* __restrict__ bhh_b,
    const float* __restrict__ Wm, const float* __restrict__ bm,
    float* __restrict__ full_enc)
{
    __shared__ __align__(16) short Hf[2 * 2 * 64 * 8];  // [ks][mt][lane][i] : h bf16, 4 KB
    __shared__ __align__(16) short Xb[2 * 2 * 64 * 8];  // [buf][mt][lane][i]: emb bf16, 4 KB

    const int tid  = threadIdx.x;
    const int lane = tid & 63;
    const int w    = __builtin_amdgcn_readfirstlane(tid >> 6);  // wave id 0..3
    const int cc   = lane & 15;
    const int quad = lane >> 4;
    const int vbase = blockIdx.x * 32;
    const int j    = w * 16 + cc;            // this lane's gate column
    const int ks_w = j >> 5;                 // which K-half of H this j lands in
    const int qa_w = (j >> 3) & 3;           // A-frag quad for this j
    const int ii_w = j & 7;                  // A-frag elem index for this j

    // emb producer mapping: threads 0..127 -> (veh = tid>>2, chunk = tid&3)
    const int ev  = tid >> 2;
    const int ech = tid & 3;
    const bool emb_on = (ev < 32);

    float h_reg[8], hf_reg[8];
    const short8 z8 = {0, 0, 0, 0, 0, 0, 0, 0};

    #pragma unroll 1
    for (int dir = 0; dir < 2; ++dir) {
        const float* Wih = dir ? Wih_b : Wih_f;
        const float* Whh = dir ? Whh_b : Whh_f;
        const float* bih = dir ? bih_b : bih_f;
        const float* bhh = dir ? bhh_b : bhh_f;

        // ---- B-frags for this wave's 16 gate columns (loaded once per dir) ----
        const int k0 = quad * 8;
        const short8 Br0 = ld8bf(Whh + (j        ) * 64 + k0);
        const short8 Br1 = ld8bf(Whh + (j        ) * 64 + 32 + k0);
        const short8 Br2 = ld8bf(Wih + (j        ) * 32 + k0);
        const short8 Bz0 = ld8bf(Whh + (j +   64) * 64 + k0);
        const short8 Bz1 = ld8bf(Whh + (j +   64) * 64 + 32 + k0);
        const short8 Bz2 = ld8bf(Wih + (j +   64) * 32 + k0);
        const short8 Bhn0 = ld8bf(Whh + (j + 128) * 64 + k0);
        const short8 Bhn1 = ld8bf(Whh + (j + 128) * 64 + 32 + k0);
        const short8 Bxn  = ld8bf(Wih + (j + 128) * 32 + k0);
        const float b_r  = bih[j] + bhh[j];
        const float b_z  = bih[j + 64] + bhh[j + 64];
        const float b_xn = bih[j + 128];
        const float b_hn = bhh[j + 128];

        #pragma unroll
        for (int i = 0; i < 8; ++i) h_reg[i] = 0.0f;

        // zero Hf (h0 = 0) and stage emb for first step into Xb[0]
        *(short8*)&Hf[tid * 8] = z8;   // 256 chunks of 16B = 4 KB
        if (emb_on) {
            const int t0 = dir ? (TT - 1) : 0;
            const int n  = vbase + ev;
            const float xs = scene[n * 32 + t0];
            const float ys = scene[n * 32 + 16 + t0];
            short8 v;
            #pragma unroll
            for (int i2 = 0; i2 < 8; ++i2) {
                const int e = ech * 8 + i2;
                v[i2] = f2bf(leakyf(fmaf(xs, W_emb[e], fmaf(ys, W_emb[EE + e], b_emb[e]))));
            }
            *(short8*)&Xb[((0 * 2 + (ev >> 4)) * 64 + ech * 16 + (ev & 15)) * 8] = v;
        }
        __syncthreads();

        #pragma unroll 1
        for (int s = 0; s < TT; ++s) {
            const int buf = s & 1;
            // ---- reads + MFMA + gate math (no LDS writes before barrier) ----
            #pragma unroll
            for (int mt = 0; mt < 2; ++mt) {
                const short8 Ah0 = *(const short8*)&Hf[((0 * 2 + mt) * 64 + lane) * 8];
                const short8 Ah1 = *(const short8*)&Hf[((1 * 2 + mt) * 64 + lane) * 8];
                const short8 Axx = *(const short8*)&Xb[((buf * 2 + mt) * 64 + lane) * 8];
                const floatx4 z4 = {0.f, 0.f, 0.f, 0.f};
                const floatx4 ar  = MFMA16(Axx, Br2, MFMA16(Ah1, Br1, MFMA16(Ah0, Br0, z4)));
                const floatx4 az  = MFMA16(Axx, Bz2, MFMA16(Ah1, Bz1, MFMA16(Ah0, Bz0, z4)));
                const floatx4 ahn = MFMA16(Ah1, Bhn1, MFMA16(Ah0, Bhn0, z4));
                const floatx4 axn = MFMA16(Axx, Bxn, z4);
                #pragma unroll
                for (int r = 0; r < 4; ++r) {
                    const float rr = sigmoidf_fast(ar[r] + b_r);
                    const float zz = sigmoidf_fast(az[r] + b_z);
                    const float ng = tanhf_fast(fmaf(rr, ahn[r] + b_hn, axn[r] + b_xn));
                    const float h0 = h_reg[mt * 4 + r];
                    h_reg[mt * 4 + r] = fmaf(zz, h0 - ng, ng);  // (1-z)*ng + z*h
                }
            }
            __syncthreads();   // all waves done reading Hf / Xb[buf]

            // ---- write new h (bf16, frag-packed) + emb for next step ----
            #pragma unroll
            for (int mt = 0; mt < 2; ++mt) {
                #pragma unroll
                for (int r = 0; r < 4; ++r) {
                    const int la = qa_w * 16 + (quad * 4 + r);   // m = quad*4+r
                    Hf[((ks_w * 2 + mt) * 64 + la) * 8 + ii_w] = f2bf(h_reg[mt * 4 + r]);
                }
            }
            if (s + 1 < TT && emb_on) {
                const int tn = dir ? (TT - 2 - s) : (s + 1);
                const int n  = vbase + ev;
                const float xs = scene[n * 32 + tn];
                const float ys = scene[n * 32 + 16 + tn];
                short8 v;
                #pragma unroll
                for (int i2 = 0; i2 < 8; ++i2) {
                    const int e = ech * 8 + i2;
                    v[i2] = f2bf(leakyf(fmaf(xs, W_emb[e], fmaf(ys, W_emb[EE + e], b_emb[e]))));
                }
                *(short8*)&Xb[(((buf ^ 1) * 2 + (ev >> 4)) * 64 + ech * 16 + (ev & 15)) * 8] = v;
            }
            __syncthreads();   // h_t / emb_{t+1} visible
        }
        if (dir == 0) {
            #pragma unroll
            for (int i = 0; i < 8; ++i) hf_reg[i] = h_reg[i];
        }
    }

    // ---- epilogue: hm = 0.5*(hf + hb); seq_enc = leaky(hm @ Wm + bm) via MFMA ----
    #pragma unroll
    for (int mt = 0; mt < 2; ++mt) {
        #pragma unroll
        for (int r = 0; r < 4; ++r) {
            const int la = qa_w * 16 + (quad * 4 + r);
            Hf[((ks_w * 2 + mt) * 64 + la) * 8 + ii_w] =
                f2bf(0.5f * (hf_reg[mt * 4 + r] + h_reg[mt * 4 + r]));
        }
    }
    __syncthreads();

    const int nt   = w >> 1;       // output n-tile (cols 0..15 / 16..31)
    const int mt_e = w & 1;        // vehicle tile
    const int n_col = nt * 16 + cc;
    short8 Bm0, Bm1;
    #pragma unroll
    for (int i = 0; i < 8; ++i) {
        Bm0[i] = f2bf(Wm[(     quad * 8 + i) * 32 + n_col]);
        Bm1[i] = f2bf(Wm[(32 + quad * 8 + i) * 32 + n_col]);
    }
    const short8 A0 = *(const short8*)&Hf[((0 * 2 + mt_e) * 64 + lane) * 8];
    const short8 A1 = *(const short8*)&Hf[((1 * 2 + mt_e) * 64 + lane) * 8];
    const floatx4 z4 = {0.f, 0.f, 0.f, 0.f};
    const floatx4 acc = MFMA16(A1, Bm1, MFMA16(A0, Bm0, z4));
    const float bmn = bm[n_col];
    #pragma unroll
    for (int r = 0; r < 4; ++r) {
        const int veh = mt_e * 16 + quad * 4 + r;
        full_enc[(vbase + veh) * HH + n_col] = leakyf(acc[r] + bmn);
    }
}

// ---------------------------------------------------------------------------
// Kernel B: spatial pairwise MLP with layer-1 factoring (unchanged from R1).
// ---------------------------------------------------------------------------
__global__ __launch_bounds__(256) void spatial_kernel(
    const float* __restrict__ scene, const int* __restrict__ index_div,
    const float* __restrict__ Ws1, const float* __restrict__ bs1,
    const float* __restrict__ Ws2, const float* __restrict__ bs2,
    float* __restrict__ full_enc)
{
    __shared__ float sfeat[NGRP][33];
    __shared__ float su[NGRP][65];
    __shared__ float szero[32];

    const int g   = blockIdx.x;
    const int tid = threadIdx.x;

    {
        const int v  = tid >> 3;
        const int c0 = (tid & 7) * 4;
        const int n  = index_div[g * NGRP + v];
        const float4 f4 = *(const float4*)(scene + n * (2 * TT) + c0);
        sfeat[v][c0 + 0] = f4.x; sfeat[v][c0 + 1] = f4.y;
        sfeat[v][c0 + 2] = f4.z; sfeat[v][c0 + 3] = f4.w;
    }
    __syncthreads();

    {
        const int v  = tid >> 3;
        const int d0 = (tid & 7) * 8;
        float acc[8];
        #pragma unroll
        for (int i = 0; i < 8; ++i) acc[i] = 0.0f;
        #pragma unroll
        for (int e = 0; e < EE; ++e) {
            const float f = sfeat[v][e];
            #pragma unroll
            for (int i = 0; i < 8; ++i) acc[i] = fmaf(f, Ws1[e * 64 + d0 + i], acc[i]);
        }
        #pragma unroll
        for (int i = 0; i < 8; ++i) su[v][d0 + i] = acc[i];
    }
    if (tid < 32) {
        float zs = bs2[tid];
        #pragma unroll
        for (int d = 0; d < HH; ++d) zs = fmaf(leakyf(bs1[d]), Ws2[d * 32 + tid], zs);
        szero[tid] = leakyf(zs);
    }
    __syncthreads();

    const int jj = tid >> 3;
    const int o  = tid & 7;

    float esum[32];
    #pragma unroll
    for (int c = 0; c < 32; ++c) esum[c] = 0.0f;

    float uj[HH];
    #pragma unroll
    for (int d = 0; d < HH; ++d) uj[d] = su[jj][d];

    #pragma unroll 1
    for (int ii = 0; ii < 4; ++ii) {
        const int i = o + ii * 8;
        float pre[32];
        #pragma unroll
        for (int c = 0; c < 32; ++c) pre[c] = bs2[c];
        #pragma unroll 8
        for (int d = 0; d < HH; ++d) {
            const float a = leakyf(su[i][d] - uj[d] + bs1[d]);
            #pragma unroll
            for (int c = 0; c < 32; ++c) pre[c] = fmaf(a, Ws2[d * 32 + c], pre[c]);
        }
        #pragma unroll
        for (int c = 0; c < 32; ++c) esum[c] += leakyf(pre[c]);
    }

    #pragma unroll
    for (int off = 1; off < 8; off <<= 1) {
        #pragma unroll
        for (int c = 0; c < 32; ++c) esum[c] += __shfl_xor(esum[c], off, 64);
    }
    if (o == 0) {
        const int row = g * NGRP + jj;
        #pragma unroll
        for (int c = 0; c < 32; ++c)
            full_enc[row * HH + 32 + c] = (esum[c] - szero[c]) * (1.0f / 31.0f);
    }
}

// ---------------------------------------------------------------------------
// Kernel C: head (unchanged from R1).
// ---------------------------------------------------------------------------
__global__ __launch_bounds__(256) void head_kernel(
    const float* __restrict__ full_enc,
    const float* __restrict__ Wo1, const float* __restrict__ bo1,
    const float* __restrict__ Wo2, const float* __restrict__ bo2,
    float* __restrict__ out)
{
    const int n = blockIdx.x * 256 + threadIdx.x;
    float t1[16];
    #pragma unroll
    for (int m = 0; m < 16; ++m) t1[m] = bo1[m];
    const float4* fe4 = (const float4*)(full_enc + n * HH);
    #pragma unroll
    for (int k4 = 0; k4 < 16; ++k4) {
        const float4 f = fe4[k4];
        const float fv[4] = {f.x, f.y, f.z, f.w};
        #pragma unroll
        for (int u = 0; u < 4; ++u) {
            const int k = k4 * 4 + u;
            #pragma unroll
            for (int m = 0; m < 16; ++m) t1[m] = fmaf(fv[u], Wo1[k * 16 + m], t1[m]);
        }
    }
    float l0 = bo2[0], l1 = bo2[1], l2 = bo2[2];
    #pragma unroll
    for (int m = 0; m < 16; ++m) {
        const float a = leakyf(t1[m]);
        l0 = fmaf(a, Wo2[m * 3 + 0], l0);
        l1 = fmaf(a, Wo2[m * 3 + 1], l1);
        l2 = fmaf(a, Wo2[m * 3 + 2], l2);
    }
    out[n * 3 + 0] = l0;
    out[n * 3 + 1] = l1;
    out[n * 3 + 2] = l2;
}

// ---------------------------------------------------------------------------
extern "C" void kernel_launch(void* const* d_in, const int* in_sizes, int n_in,
                              void* d_out, int out_size, void* d_ws, size_t ws_size,
                              hipStream_t stream) {
    const float* scene     = (const float*)d_in[0];
    const int*   index_div = (const int*)d_in[4];
    const float* W_emb = (const float*)d_in[5];
    const float* b_emb = (const float*)d_in[6];
    const float* Wih_f = (const float*)d_in[7];
    const float* Whh_f = (const float*)d_in[8];
    const float* bih_f = (const float*)d_in[9];
    const float* bhh_f = (const float*)d_in[10];
    const float* Wih_b = (const float*)d_in[11];
    const float* Whh_b = (const float*)d_in[12];
    const float* bih_b = (const float*)d_in[13];
    const float* bhh_b = (const float*)d_in[14];
    const float* Wm  = (const float*)d_in[15];
    const float* bm  = (const float*)d_in[16];
    const float* Ws1 = (const float*)d_in[17];
    const float* bs1 = (const float*)d_in[18];
    const float* Ws2 = (const float*)d_in[19];
    const float* bs2 = (const float*)d_in[20];
    const float* Wo1 = (const float*)d_in[21];
    const float* bo1 = (const float*)d_in[22];
    const float* Wo2 = (const float*)d_in[23];
    const float* bo2 = (const float*)d_in[24];

    const int N = in_sizes[0] / (2 * TT);   // 32768
    const int G = in_sizes[4] / NGRP;       // 1024

    float* out      = (float*)d_out;
    float* full_enc = out + (size_t)N * CC;

    gru_mfma_kernel<<<dim3(N / 32), dim3(256), 0, stream>>>(
        scene, W_emb, b_emb, Wih_f, Whh_f, bih_f, bhh_f,
        Wih_b, Whh_b, bih_b, bhh_b, Wm, bm, full_enc);

    spatial_kernel<<<dim3(G), dim3(256), 0, stream>>>(
        scene, index_div, Ws1, bs1, Ws2, bs2, full_enc);

    head_kernel<<<dim3(N / 256), dim3(256), 0, stream>>>(
        full_enc, Wo1, bo1, Wo2, bo2, out);
}

// Round 4
// 226.295 us; speedup vs baseline: 5.2528x; 1.3041x over previous
//
#include <hip/hip_runtime.h>
#include <hip/hip_bf16.h>

#define TT 16      // in_length
#define EE 32      // embedding size
#define HH 64      // encoder size
#define NGRP 32    // vehicles per group
#define CC 3       // classes

typedef __attribute__((ext_vector_type(8))) short short8;
typedef __attribute__((ext_vector_type(4))) float floatx4;

#define MFMA16(a, b, c) __builtin_amdgcn_mfma_f32_16x16x32_bf16((a), (b), (c), 0, 0, 0)

__device__ __forceinline__ float leakyf(float x) { return fmaxf(x, 0.1f * x); }
__device__ __forceinline__ float sigmoidf_fast(float x) {
    return __builtin_amdgcn_rcpf(1.0f + __expf(-x));
}
__device__ __forceinline__ float tanhf_fast(float x) {
    return 1.0f - 2.0f * __builtin_amdgcn_rcpf(__expf(2.0f * x) + 1.0f);
}
__device__ __forceinline__ short f2bf(float x) {   // fp32 -> bf16 RNE
    unsigned u = __float_as_uint(x);
    return (short)((u + 0x7FFFu + ((u >> 16) & 1u)) >> 16);
}
__device__ __forceinline__ float bf2f(short s) {
    return __uint_as_float(((unsigned)(unsigned short)s) << 16);
}
__device__ __forceinline__ short8 ld8bf(const float* __restrict__ p) {
    const float4 a = *(const float4*)p;
    const float4 b = *(const float4*)(p + 4);
    short8 v;
    v[0] = f2bf(a.x); v[1] = f2bf(a.y); v[2] = f2bf(a.z); v[3] = f2bf(a.w);
    v[4] = f2bf(b.x); v[5] = f2bf(b.y); v[6] = f2bf(b.z); v[7] = f2bf(b.w);
    return v;
}

// ---------------------------------------------------------------------------
// Kernel A (MFMA): both GRU directions concurrently. Block = 512 thr = 8 waves:
// waves 0-3 forward (wd = gate-column quarter), waves 4-7 backward.
// emb precomputed ONCE for all 16 t into frag-packed LDS (both dirs reuse).
//   A-frag: A[m=lane&15][k=(lane>>4)*8+i]   B-frag: B[k][n=lane&15]
//   C/D   : row=(lane>>4)*4+reg, col=lane&15
// ---------------------------------------------------------------------------
__global__ __launch_bounds__(512, 6) void gru_mfma_kernel(
    const float* __restrict__ scene,
    const float* __restrict__ W_emb, const float* __restrict__ b_emb,
    const float* __restrict__ Wih_f, const float* __restrict__ Whh_f,
    const float* __restrict__ bih_f, const float* __restrict__ bhh_f,
    const float* __restrict__ Wih_b, const float* __restrict__ Whh_b,
    const float* __restrict__ bih_b, const float* __restrict__ bhh_b,
    const float* __restrict__ Wm, const float* __restrict__ bm,
    float* __restrict__ full_enc)
{
    __shared__ __align__(16) short Xall[16 * 2 * 64 * 8];     // [t][mt][lane][i]  32 KB
    __shared__ __align__(16) short Hf[2 * 2 * 2 * 64 * 8];    // [dir][ks][mt][lane][i] 8 KB

    const int tid  = threadIdx.x;
    const int lane = tid & 63;
    const int w    = __builtin_amdgcn_readfirstlane(tid >> 6);  // 0..7
    const int dir  = w >> 2;
    const int wd   = w & 3;
    const int cc   = lane & 15;
    const int quad = lane >> 4;
    const int vbase = blockIdx.x * 32;
    const int j    = wd * 16 + cc;            // gate column
    const int ks_w = j >> 5;
    const int qa_w = (j >> 3) & 3;
    const int ii_w = j & 7;

    // ---- prologue: emb for ALL t (512 threads = 16 t x 32 veh, one each) ----
    {
        const int t   = tid >> 5;
        const int veh = tid & 31;
        const int n   = vbase + veh;
        const float xs = scene[n * 32 + t];
        const float ys = scene[n * 32 + 16 + t];
        const int mt = veh >> 4;
        const int m  = veh & 15;
        #pragma unroll
        for (int q = 0; q < 4; ++q) {
            short8 v;
            #pragma unroll
            for (int i2 = 0; i2 < 8; ++i2) {
                const int e = q * 8 + i2;
                v[i2] = f2bf(leakyf(fmaf(xs, W_emb[e], fmaf(ys, W_emb[EE + e], b_emb[e]))));
            }
            *(short8*)&Xall[(((t * 2 + mt) * 64) + q * 16 + m) * 8] = v;
        }
        const short8 z8 = {0, 0, 0, 0, 0, 0, 0, 0};
        *(short8*)&Hf[tid * 8] = z8;   // 512 x 16B = 8 KB (h0 = 0, both dirs)
    }

    // ---- per-wave B-frags (this wave's dir + 16 gate columns) ----
    const float* Wih = dir ? Wih_b : Wih_f;
    const float* Whh = dir ? Whh_b : Whh_f;
    const float* bih = dir ? bih_b : bih_f;
    const float* bhh = dir ? bhh_b : bhh_f;
    const int k0 = quad * 8;
    const short8 Br0  = ld8bf(Whh + (j      ) * 64 + k0);
    const short8 Br1  = ld8bf(Whh + (j      ) * 64 + 32 + k0);
    const short8 Br2  = ld8bf(Wih + (j      ) * 32 + k0);
    const short8 Bz0  = ld8bf(Whh + (j +  64) * 64 + k0);
    const short8 Bz1  = ld8bf(Whh + (j +  64) * 64 + 32 + k0);
    const short8 Bz2  = ld8bf(Wih + (j +  64) * 32 + k0);
    const short8 Bhn0 = ld8bf(Whh + (j + 128) * 64 + k0);
    const short8 Bhn1 = ld8bf(Whh + (j + 128) * 64 + 32 + k0);
    const short8 Bxn  = ld8bf(Wih + (j + 128) * 32 + k0);
    const float b_r  = bih[j] + bhh[j];
    const float b_z  = bih[j + 64] + bhh[j + 64];
    const float b_xn = bih[j + 128];
    const float b_hn = bhh[j + 128];

    float h_reg[8];
    #pragma unroll
    for (int i = 0; i < 8; ++i) h_reg[i] = 0.0f;

    short* HfD = &Hf[dir * (2 * 2 * 64 * 8)];
    __syncthreads();

    #pragma unroll 1
    for (int s = 0; s < TT; ++s) {
        const int t = dir ? (TT - 1 - s) : s;
        #pragma unroll
        for (int mt = 0; mt < 2; ++mt) {
            const short8 Ah0 = *(const short8*)&HfD[((0 * 2 + mt) * 64 + lane) * 8];
            const short8 Ah1 = *(const short8*)&HfD[((1 * 2 + mt) * 64 + lane) * 8];
            const short8 Axx = *(const short8*)&Xall[((t * 2 + mt) * 64 + lane) * 8];
            const floatx4 z4 = {0.f, 0.f, 0.f, 0.f};
            const floatx4 ar  = MFMA16(Axx, Br2, MFMA16(Ah1, Br1, MFMA16(Ah0, Br0, z4)));
            const floatx4 az  = MFMA16(Axx, Bz2, MFMA16(Ah1, Bz1, MFMA16(Ah0, Bz0, z4)));
            const floatx4 ahn = MFMA16(Ah1, Bhn1, MFMA16(Ah0, Bhn0, z4));
            const floatx4 axn = MFMA16(Axx, Bxn, z4);
            #pragma unroll
            for (int r = 0; r < 4; ++r) {
                const float rr = sigmoidf_fast(ar[r] + b_r);
                const float zz = sigmoidf_fast(az[r] + b_z);
                const float ng = tanhf_fast(fmaf(rr, ahn[r] + b_hn, axn[r] + b_xn));
                const float h0 = h_reg[mt * 4 + r];
                h_reg[mt * 4 + r] = fmaf(zz, h0 - ng, ng);  // (1-z)*ng + z*h
            }
        }
        __syncthreads();   // all reads of Hf done
        #pragma unroll
        for (int mt = 0; mt < 2; ++mt) {
            #pragma unroll
            for (int r = 0; r < 4; ++r) {
                const int la = qa_w * 16 + (quad * 4 + r);
                HfD[((ks_w * 2 + mt) * 64 + la) * 8 + ii_w] = f2bf(h_reg[mt * 4 + r]);
            }
        }
        __syncthreads();   // h_t visible
    }

    // ---- epilogue: Hf[0]=h_f, Hf[1]=h_b (bf16 frags). Waves 0-3 compute seq_enc.
    if (w < 4) {
        const int nt   = w >> 1;
        const int mt_e = w & 1;
        const int n_col = nt * 16 + cc;
        short8 Bm0, Bm1;
        #pragma unroll
        for (int i = 0; i < 8; ++i) {
            Bm0[i] = f2bf(Wm[(     quad * 8 + i) * 32 + n_col]);
            Bm1[i] = f2bf(Wm[(32 + quad * 8 + i) * 32 + n_col]);
        }
        short8 A0, A1;
        #pragma unroll
        for (int ks = 0; ks < 2; ++ks) {
            const short8 F = *(const short8*)&Hf[(((0 * 2 + ks) * 2 + mt_e) * 64 + lane) * 8];
            const short8 B = *(const short8*)&Hf[(((1 * 2 + ks) * 2 + mt_e) * 64 + lane) * 8];
            #pragma unroll
            for (int i = 0; i < 8; ++i) {
                const short v = f2bf(0.5f * (bf2f(F[i]) + bf2f(B[i])));
                if (ks == 0) A0[i] = v; else A1[i] = v;
            }
        }
        const floatx4 z4 = {0.f, 0.f, 0.f, 0.f};
        const floatx4 acc = MFMA16(A1, Bm1, MFMA16(A0, Bm0, z4));
        const float bmn = bm[n_col];
        #pragma unroll
        for (int r = 0; r < 4; ++r) {
            const int veh = mt_e * 16 + quad * 4 + r;
            full_enc[(vbase + veh) * HH + n_col] = leakyf(acc[r] + bmn);
        }
    }
}

// ---------------------------------------------------------------------------
// Kernel B (MFMA): spatial pairwise MLP. One block per group, 4 waves.
// FIX (R3 bug): wave w handles j in [8w, 8w+8) — 4 waves x 8 = 32 j's total.
// (R3 used 16 j's/wave => j up to 63: OOB su reads + clobbered other groups.)
// Per j: A = leaky(u_i - u_j + bs1) built on the fly (bf16, rows = i),
// B = Ws2 frags in regs, leaky(D + bs2) accumulated, quad-shuffle reduce over i.
// ---------------------------------------------------------------------------
__global__ __launch_bounds__(256, 4) void spatial_mfma_kernel(
    const float* __restrict__ scene, const int* __restrict__ index_div,
    const float* __restrict__ Ws1, const float* __restrict__ bs1,
    const float* __restrict__ Ws2, const float* __restrict__ bs2,
    float* __restrict__ full_enc)
{
    __shared__ float sfeat[NGRP][33];
    __shared__ float su[NGRP][68];    // stride 68: float4-aligned rows
    __shared__ float szero[32];

    const int g    = blockIdx.x;
    const int tid  = threadIdx.x;
    const int lane = tid & 63;
    const int w    = __builtin_amdgcn_readfirstlane(tid >> 6);
    const int cc   = lane & 15;
    const int quad = lane >> 4;

    // stage feat (gather)
    {
        const int v  = tid >> 3;
        const int c0 = (tid & 7) * 4;
        const int n  = index_div[g * NGRP + v];
        const float4 f4 = *(const float4*)(scene + n * (2 * TT) + c0);
        sfeat[v][c0 + 0] = f4.x; sfeat[v][c0 + 1] = f4.y;
        sfeat[v][c0 + 2] = f4.z; sfeat[v][c0 + 3] = f4.w;
    }
    __syncthreads();

    // u = feat @ Ws1 (no bias; bs1 folded into the pair diff)
    {
        const int v  = tid >> 3;
        const int d0 = (tid & 7) * 8;
        float acc[8];
        #pragma unroll
        for (int i = 0; i < 8; ++i) acc[i] = 0.0f;
        #pragma unroll
        for (int e = 0; e < EE; ++e) {
            const float f = sfeat[v][e];
            const float4 w0 = *(const float4*)&Ws1[e * 64 + d0];
            const float4 w1 = *(const float4*)&Ws1[e * 64 + d0 + 4];
            acc[0] = fmaf(f, w0.x, acc[0]); acc[1] = fmaf(f, w0.y, acc[1]);
            acc[2] = fmaf(f, w0.z, acc[2]); acc[3] = fmaf(f, w0.w, acc[3]);
            acc[4] = fmaf(f, w1.x, acc[4]); acc[5] = fmaf(f, w1.y, acc[5]);
            acc[6] = fmaf(f, w1.z, acc[6]); acc[7] = fmaf(f, w1.w, acc[7]);
        }
        #pragma unroll
        for (int i = 0; i < 8; ++i) su[v][d0 + i] = acc[i];
    }
    // zero_enc
    if (tid < 32) {
        float zs = bs2[tid];
        #pragma unroll
        for (int d = 0; d < HH; ++d) zs = fmaf(leakyf(bs1[d]), Ws2[d * 32 + tid], zs);
        szero[tid] = leakyf(zs);
    }

    // B-frags: Ws2 (64x32) -> [nhalf][ktile], and per-lane bs1/bs2 slices
    short8 Bw00, Bw01, Bw10, Bw11;
    #pragma unroll
    for (int i = 0; i < 8; ++i) {
        Bw00[i] = f2bf(Ws2[(     quad * 8 + i) * 32 + cc]);
        Bw01[i] = f2bf(Ws2[(32 + quad * 8 + i) * 32 + cc]);
        Bw10[i] = f2bf(Ws2[(     quad * 8 + i) * 32 + 16 + cc]);
        Bw11[i] = f2bf(Ws2[(32 + quad * 8 + i) * 32 + 16 + cc]);
    }
    float bsq0[8], bsq1[8];
    #pragma unroll
    for (int i = 0; i < 8; ++i) {
        bsq0[i] = bs1[quad * 8 + i];
        bsq1[i] = bs1[32 + quad * 8 + i];
    }
    const float bs2c0 = bs2[cc], bs2c1 = bs2[16 + cc];
    __syncthreads();

    #pragma unroll 2
    for (int jj = 0; jj < 8; ++jj) {
        const int jrow = w * 8 + jj;       // wave-uniform j, 0..31
        float vj0[8], vj1[8];
        #pragma unroll
        for (int i = 0; i < 8; ++i) {
            vj0[i] = su[jrow][quad * 8 + i] - bsq0[i];
            vj1[i] = su[jrow][32 + quad * 8 + i] - bsq1[i];
        }
        float acc0 = 0.0f, acc1 = 0.0f;
        #pragma unroll
        for (int it = 0; it < 2; ++it) {
            const int irow = it * 16 + cc;   // A-frag row m = cc
            const float4 p0 = *(const float4*)&su[irow][quad * 8];
            const float4 p1 = *(const float4*)&su[irow][quad * 8 + 4];
            const float4 p2 = *(const float4*)&su[irow][32 + quad * 8];
            const float4 p3 = *(const float4*)&su[irow][32 + quad * 8 + 4];
            short8 A0, A1;
            A0[0] = f2bf(leakyf(p0.x - vj0[0])); A0[1] = f2bf(leakyf(p0.y - vj0[1]));
            A0[2] = f2bf(leakyf(p0.z - vj0[2])); A0[3] = f2bf(leakyf(p0.w - vj0[3]));
            A0[4] = f2bf(leakyf(p1.x - vj0[4])); A0[5] = f2bf(leakyf(p1.y - vj0[5]));
            A0[6] = f2bf(leakyf(p1.z - vj0[6])); A0[7] = f2bf(leakyf(p1.w - vj0[7]));
            A1[0] = f2bf(leakyf(p2.x - vj1[0])); A1[1] = f2bf(leakyf(p2.y - vj1[1]));
            A1[2] = f2bf(leakyf(p2.z - vj1[2])); A1[3] = f2bf(leakyf(p2.w - vj1[3]));
            A1[4] = f2bf(leakyf(p3.x - vj1[4])); A1[5] = f2bf(leakyf(p3.y - vj1[5]));
            A1[6] = f2bf(leakyf(p3.z - vj1[6])); A1[7] = f2bf(leakyf(p3.w - vj1[7]));
            const floatx4 z4 = {0.f, 0.f, 0.f, 0.f};
            const floatx4 D0 = MFMA16(A1, Bw01, MFMA16(A0, Bw00, z4));
            const floatx4 D1 = MFMA16(A1, Bw11, MFMA16(A0, Bw10, z4));
            #pragma unroll
            for (int r = 0; r < 4; ++r) {
                acc0 += leakyf(D0[r] + bs2c0);
                acc1 += leakyf(D1[r] + bs2c1);
            }
        }
        // reduce over quads (rows i)
        acc0 += __shfl_xor(acc0, 16, 64); acc0 += __shfl_xor(acc0, 32, 64);
        acc1 += __shfl_xor(acc1, 16, 64); acc1 += __shfl_xor(acc1, 32, 64);
        const int row = g * NGRP + jrow;
        if (quad == 0)
            full_enc[row * HH + 32 + cc] = (acc0 - szero[cc]) * (1.0f / 31.0f);
        else if (quad == 1)
            full_enc[row * HH + 48 + cc] = (acc1 - szero[16 + cc]) * (1.0f / 31.0f);
    }
}

// ---------------------------------------------------------------------------
// Kernel C: head — x_logit = leaky(full_enc @ Wo1 + bo1) @ Wo2 + bo2
// ---------------------------------------------------------------------------
__global__ __launch_bounds__(64) void head_kernel(
    const float* __restrict__ full_enc,
    const float* __restrict__ Wo1, const float* __restrict__ bo1,
    const float* __restrict__ Wo2, const float* __restrict__ bo2,
    float* __restrict__ out)
{
    const int n = blockIdx.x * 64 + threadIdx.x;
    float t1[16];
    #pragma unroll
    for (int m = 0; m < 16; ++m) t1[m] = bo1[m];
    const float4* fe4 = (const float4*)(full_enc + n * HH);
    #pragma unroll
    for (int k4 = 0; k4 < 16; ++k4) {
        const float4 f = fe4[k4];
        const float fv[4] = {f.x, f.y, f.z, f.w};
        #pragma unroll
        for (int u = 0; u < 4; ++u) {
            const int k = k4 * 4 + u;
            #pragma unroll
            for (int m = 0; m < 16; ++m) t1[m] = fmaf(fv[u], Wo1[k * 16 + m], t1[m]);
        }
    }
    float l0 = bo2[0], l1 = bo2[1], l2 = bo2[2];
    #pragma unroll
    for (int m = 0; m < 16; ++m) {
        const float a = leakyf(t1[m]);
        l0 = fmaf(a, Wo2[m * 3 + 0], l0);
        l1 = fmaf(a, Wo2[m * 3 + 1], l1);
        l2 = fmaf(a, Wo2[m * 3 + 2], l2);
    }
    out[n * 3 + 0] = l0;
    out[n * 3 + 1] = l1;
    out[n * 3 + 2] = l2;
}

// ---------------------------------------------------------------------------
extern "C" void kernel_launch(void* const* d_in, const int* in_sizes, int n_in,
                              void* d_out, int out_size, void* d_ws, size_t ws_size,
                              hipStream_t stream) {
    const float* scene     = (const float*)d_in[0];
    const int*   index_div = (const int*)d_in[4];
    const float* W_emb = (const float*)d_in[5];
    const float* b_emb = (const float*)d_in[6];
    const float* Wih_f = (const float*)d_in[7];
    const float* Whh_f = (const float*)d_in[8];
    const float* bih_f = (const float*)d_in[9];
    const float* bhh_f = (const float*)d_in[10];
    const float* Wih_b = (const float*)d_in[11];
    const float* Whh_b = (const float*)d_in[12];
    const float* bih_b = (const float*)d_in[13];
    const float* bhh_b = (const float*)d_in[14];
    const float* Wm  = (const float*)d_in[15];
    const float* bm  = (const float*)d_in[16];
    const float* Ws1 = (const float*)d_in[17];
    const float* bs1 = (const float*)d_in[18];
    const float* Ws2 = (const float*)d_in[19];
    const float* bs2 = (const float*)d_in[20];
    const float* Wo1 = (const float*)d_in[21];
    const float* bo1 = (const float*)d_in[22];
    const float* Wo2 = (const float*)d_in[23];
    const float* bo2 = (const float*)d_in[24];

    const int N = in_sizes[0] / (2 * TT);   // 32768
    const int G = in_sizes[4] / NGRP;       // 1024

    float* out      = (float*)d_out;
    float* full_enc = out + (size_t)N * CC;

    gru_mfma_kernel<<<dim3(N / 32), dim3(512), 0, stream>>>(
        scene, W_emb, b_emb, Wih_f, Whh_f, bih_f, bhh_f,
        Wih_b, Whh_b, bih_b, bhh_b, Wm, bm, full_enc);

    spatial_mfma_kernel<<<dim3(G), dim3(256), 0, stream>>>(
        scene, index_div, Ws1, bs1, Ws2, bs2, full_enc);

    head_kernel<<<dim3(N / 64), dim3(64), 0, stream>>>(
        full_enc, Wo1, bo1, Wo2, bo2, out);
}